// Round 1
// baseline (274.411 us; speedup 1.0000x reference)
//
#include <hip/hip_runtime.h>
#include <math.h>

// Shapes fixed by the reference setup_inputs():
// B=2, S=8192, H=2048, P=512, N=64
constexpr int Hc   = 2048;
constexpr int Pc   = 512;
constexpr int Nc   = 64;
constexpr int ROWS = 16384;          // B*S
constexpr int SUMB = 512;            // partial-sum blocks
constexpr int ROWS_PER_B = ROWS / SUMB;  // 32

// ---- output layout (floats), reference return order ----
constexpr int O_SUR  = 0;
constexpr int O_PERR = 1;
constexpr int O_PRED = O_PERR + Hc;      // 2049
constexpr int O_MEM  = O_PRED + Hc;      // 4097
constexpr int O_MEMS = O_MEM + Nc * Hc;  // 135169
constexpr int O_NPS  = O_MEMS + Nc;      // 135233  (total 135745)

// ---- workspace layout (floats) ----
constexpr size_t WS_PART = 0;                       // SUMB*Hc = 1,048,576
constexpr size_t WS_ACT  = (size_t)SUMB * Hc;       // Hc
constexpr size_t WS_XGRU = WS_ACT + Hc;             // Hc
constexpr size_t WS_GH   = WS_XGRU + Hc;            // 3P = 1536
constexpr size_t WS_ERR2 = WS_GH + 1536;            // 8

__device__ __forceinline__ float warp_dot(const float* __restrict__ w,
                                          const float* __restrict__ x, int len) {
    int lane = threadIdx.x & 63;
    float s = 0.f;
    for (int i = lane * 4; i < len; i += 64 * 4) {
        float4 wv = *(const float4*)(w + i);
        float4 xv = *(const float4*)(x + i);
        s += wv.x * xv.x + wv.y * xv.y + wv.z * xv.z + wv.w * xv.w;
    }
    #pragma unroll
    for (int off = 32; off; off >>= 1) s += __shfl_xor(s, off);
    return s;
}

// K1: everything independent of `actual`:
//  - blocks [0,512):      hidden_states column partial sums (32 rows each)
//  - blocks [512,640):    predicted = pred_proj_w @ pred_state (16 rows/block)
//  - blocks [640,736):    gh = W_hh @ pred_state (16 rows/block)
//  - blocks [736,768):    mem_states copy + mem_strength decay
__global__ __launch_bounds__(256) void k1(const float* __restrict__ hs,
                                          const float* __restrict__ pred_state,
                                          const float* __restrict__ mem_states,
                                          const float* __restrict__ mem_strength,
                                          const float* __restrict__ W_hh,
                                          const float* __restrict__ pred_proj_w,
                                          float* __restrict__ out,
                                          float* __restrict__ ws) {
    const int bid = blockIdx.x, t = threadIdx.x;
    if (bid < SUMB) {
        float4 a0 = make_float4(0.f, 0.f, 0.f, 0.f);
        float4 a1 = make_float4(0.f, 0.f, 0.f, 0.f);
        const float* base = hs + (size_t)bid * ROWS_PER_B * Hc;
        for (int r = 0; r < ROWS_PER_B; ++r) {
            const float4* rp = (const float4*)(base + (size_t)r * Hc);
            float4 v0 = rp[t];
            float4 v1 = rp[t + 256];
            a0.x += v0.x; a0.y += v0.y; a0.z += v0.z; a0.w += v0.w;
            a1.x += v1.x; a1.y += v1.y; a1.z += v1.z; a1.w += v1.w;
        }
        float4* wp = (float4*)(ws + WS_PART + (size_t)bid * Hc);
        wp[t] = a0;
        wp[t + 256] = a1;
    } else if (bid < SUMB + 128) {
        int base_row = (bid - SUMB) * 16 + (t >> 6) * 4;
        #pragma unroll
        for (int rr = 0; rr < 4; ++rr) {
            int row = base_row + rr;
            float d = warp_dot(pred_proj_w + (size_t)row * Pc, pred_state, Pc);
            if ((t & 63) == 0) out[O_PRED + row] = d;
        }
    } else if (bid < SUMB + 224) {
        int base_row = (bid - (SUMB + 128)) * 16 + (t >> 6) * 4;
        #pragma unroll
        for (int rr = 0; rr < 4; ++rr) {
            int row = base_row + rr;
            float d = warp_dot(W_hh + (size_t)row * Pc, pred_state, Pc);
            if ((t & 63) == 0) ws[WS_GH + row] = d;
        }
    } else {
        int cb = bid - (SUMB + 224);     // 0..31
        #pragma unroll
        for (int i = 0; i < 16; ++i) {
            int idx = (cb * 16 + i) * 256 + t;   // covers 64*2048 = 131072
            out[O_MEM + idx] = mem_states[idx];
        }
        if (cb == 0 && t < Nc) {
            double ds = pow(0.999, 8192.0);      // DECAY ** seq_len
            out[O_MEMS + t] = mem_strength[t] * (float)ds;
        }
    }
}

// K2: finalize actual, prediction_error, squared-error partials. 8 blocks x 256.
__global__ __launch_bounds__(256) void k2(float* __restrict__ out,
                                          float* __restrict__ ws) {
    const int c = blockIdx.x * 256 + threadIdx.x;   // column 0..2047
    float s = 0.f;
    #pragma unroll 8
    for (int p = 0; p < SUMB; ++p) s += ws[WS_PART + (size_t)p * Hc + c];
    float actual = s * (1.0f / (float)ROWS);
    ws[WS_ACT + c] = actual;
    float pe = actual - out[O_PRED + c];
    out[O_PERR + c] = pe;
    float e2 = pe * pe;
    #pragma unroll
    for (int off = 32; off; off >>= 1) e2 += __shfl_xor(e2, off);
    __shared__ float sm[4];
    if ((threadIdx.x & 63) == 0) sm[threadIdx.x >> 6] = e2;
    __syncthreads();
    if (threadIdx.x == 0) ws[WS_ERR2 + blockIdx.x] = sm[0] + sm[1] + sm[2] + sm[3];
}

// K3: blocks [0,512): x_gru = input_proj_w @ actual (wave-per-row, 4 rows/block)
//     block 512:      surprise + slot writes
__global__ __launch_bounds__(256) void k3(const float* __restrict__ input_proj_w,
                                          const float* __restrict__ surprise_scale,
                                          const int* __restrict__ write_ptr,
                                          float* __restrict__ out,
                                          float* __restrict__ ws) {
    const int bid = blockIdx.x;
    if (bid < 512) {
        int row = bid * 4 + (threadIdx.x >> 6);
        float d = warp_dot(input_proj_w + (size_t)row * Hc, ws + WS_ACT, Hc);
        if ((threadIdx.x & 63) == 0) ws[WS_XGRU + row] = d;
    } else {
        __shared__ float s_sur;
        __shared__ int s_slot;
        if (threadIdx.x == 0) {
            float e2 = 0.f;
            #pragma unroll
            for (int i = 0; i < 8; ++i) e2 += ws[WS_ERR2 + i];
            float norm = sqrtf(e2 * (1.0f / (float)Hc));
            float sur = 1.f / (1.f + expf(-surprise_scale[0] * norm));
            out[O_SUR] = sur;
            int slot = write_ptr[0] % Nc;
            if (slot < 0) slot += Nc;
            out[O_MEMS + slot] = sur;
            s_sur = sur;
            s_slot = slot;
        }
        __syncthreads();
        float sur = s_sur;
        int slot = s_slot;
        for (int c = threadIdx.x; c < Hc; c += 256)
            out[O_MEM + (size_t)slot * Hc + c] = ws[WS_ACT + c] * sur;
    }
}

// K4: gi = W_ih @ x_gru + fused GRU combine. 128 blocks; block j owns output
// elements k0=4j..4j+3, computing rows {g*512 + k0 + e} for gate g in {r,z,n}.
__global__ __launch_bounds__(256) void k4(const float* __restrict__ W_ih,
                                          const float* __restrict__ b_ih,
                                          const float* __restrict__ b_hh,
                                          const float* __restrict__ pred_state,
                                          float* __restrict__ out,
                                          float* __restrict__ ws) {
    const int k0 = blockIdx.x * 4;
    const int wave = threadIdx.x >> 6;
    __shared__ float gi_s[12];
    #pragma unroll
    for (int j = 0; j < 3; ++j) {
        int d = wave * 3 + j;           // 0..11
        int g = d >> 2, e = d & 3;
        int row = g * 512 + k0 + e;
        float v = warp_dot(W_ih + (size_t)row * Hc, ws + WS_XGRU, Hc);
        if ((threadIdx.x & 63) == 0) gi_s[d] = v;
    }
    __syncthreads();
    if (threadIdx.x < 4) {
        int k = k0 + threadIdx.x;
        float i_r = gi_s[threadIdx.x]     + b_ih[k];
        float i_z = gi_s[4 + threadIdx.x] + b_ih[512 + k];
        float i_n = gi_s[8 + threadIdx.x] + b_ih[1024 + k];
        float h_r = ws[WS_GH + k]        + b_hh[k];
        float h_z = ws[WS_GH + 512 + k]  + b_hh[512 + k];
        float h_n = ws[WS_GH + 1024 + k] + b_hh[1024 + k];
        float r = 1.f / (1.f + expf(-(i_r + h_r)));
        float z = 1.f / (1.f + expf(-(i_z + h_z)));
        float n = tanhf(i_n + r * h_n);
        float h = pred_state[k];
        out[O_NPS + k] = (1.f - z) * n + z * h;
    }
}

extern "C" void kernel_launch(void* const* d_in, const int* in_sizes, int n_in,
                              void* d_out, int out_size, void* d_ws, size_t ws_size,
                              hipStream_t stream) {
    const float* hs            = (const float*)d_in[0];
    const float* pred_state    = (const float*)d_in[1];
    const float* mem_states    = (const float*)d_in[2];
    const float* mem_strength  = (const float*)d_in[3];
    const float* W_ih          = (const float*)d_in[4];
    const float* W_hh          = (const float*)d_in[5];
    const float* b_ih          = (const float*)d_in[6];
    const float* b_hh          = (const float*)d_in[7];
    const float* pred_proj_w   = (const float*)d_in[8];
    const float* input_proj_w  = (const float*)d_in[9];
    const float* surprise_scale= (const float*)d_in[10];
    const int*   write_ptr     = (const int*)d_in[11];
    float* out = (float*)d_out;
    float* ws  = (float*)d_ws;

    k1<<<768, 256, 0, stream>>>(hs, pred_state, mem_states, mem_strength,
                                W_hh, pred_proj_w, out, ws);
    k2<<<8, 256, 0, stream>>>(out, ws);
    k3<<<513, 256, 0, stream>>>(input_proj_w, surprise_scale, write_ptr, out, ws);
    k4<<<128, 256, 0, stream>>>(W_ih, b_ih, b_hh, pred_state, out, ws);
}

// Round 2
// 263.856 us; speedup vs baseline: 1.0400x; 1.0400x over previous
//
#include <hip/hip_runtime.h>
#include <math.h>

// Shapes fixed by the reference setup_inputs():
// B=2, S=8192, H=2048, P=512, N=64
constexpr int Hc   = 2048;
constexpr int Pc   = 512;
constexpr int Nc   = 64;
constexpr int ROWS = 16384;          // B*S

// k1 sum geometry: 16 row-chunks x 128 col-chunks = 2048 blocks.
// Each block: 1024 rows x 16 cols. Partials: [16][2048] = 128 KB.
constexpr int RCHUNKS = 16;
constexpr int CCHUNKS = 128;
constexpr int SUMB    = RCHUNKS * CCHUNKS;   // 2048
constexpr int ROWS_PER_CHUNK = ROWS / RCHUNKS;  // 1024

// k1 extra blocks
constexpr int B_PRED0 = SUMB;            // 128 blocks: predicted (2048 rows)
constexpr int B_GH0   = SUMB + 128;      // 96 blocks: gh (1536 rows)
constexpr int B_CPY0  = SUMB + 224;      // 32 blocks: mem copy + decay
constexpr int K1_GRID = SUMB + 256;      // 2304

// ---- output layout (floats), reference return order ----
constexpr int O_SUR  = 0;
constexpr int O_PERR = 1;
constexpr int O_PRED = O_PERR + Hc;      // 2049
constexpr int O_MEM  = O_PRED + Hc;      // 4097
constexpr int O_MEMS = O_MEM + Nc * Hc;  // 135169
constexpr int O_NPS  = O_MEMS + Nc;      // 135233  (total 135745)

// ---- workspace layout (floats) ----
constexpr size_t WS_PART = 0;                        // RCHUNKS*Hc = 32768
constexpr size_t WS_ACT  = (size_t)RCHUNKS * Hc;     // Hc
constexpr size_t WS_XGRU = WS_ACT + Hc;              // Hc
constexpr size_t WS_GH   = WS_XGRU + Hc;             // 3P = 1536
constexpr size_t WS_ERR2 = WS_GH + 1536;             // 8

__device__ __forceinline__ float warp_dot(const float* __restrict__ w,
                                          const float* __restrict__ x, int len) {
    int lane = threadIdx.x & 63;
    float s = 0.f;
    for (int i = lane * 4; i < len; i += 64 * 4) {
        float4 wv = *(const float4*)(w + i);
        float4 xv = *(const float4*)(x + i);
        s += wv.x * xv.x + wv.y * xv.y + wv.z * xv.z + wv.w * xv.w;
    }
    #pragma unroll
    for (int off = 32; off; off >>= 1) s += __shfl_xor(s, off);
    return s;
}

// K1: everything independent of `actual`:
//  - blocks [0,2048):        hidden_states column partial sums (column-stripe,
//                            block = 1024 rows x 16 cols, in-block reduction)
//  - blocks [2048,2176):     predicted = pred_proj_w @ pred_state
//  - blocks [2176,2272):     gh = W_hh @ pred_state
//  - blocks [2272,2304):     mem_states copy + mem_strength decay
__global__ __launch_bounds__(256, 4) void k1(const float* __restrict__ hs,
                                             const float* __restrict__ pred_state,
                                             const float* __restrict__ mem_states,
                                             const float* __restrict__ mem_strength,
                                             const float* __restrict__ W_hh,
                                             const float* __restrict__ pred_proj_w,
                                             float* __restrict__ out,
                                             float* __restrict__ ws) {
    const int bid = blockIdx.x, t = threadIdx.x;
    if (bid < SUMB) {
        const int rowchunk = bid >> 7;        // 0..15
        const int colchunk = bid & 127;       // 0..127
        const int cf = t & 3;                 // float4 within 16-col stripe
        const int r0 = t >> 2;                // 0..63
        const float* base = hs + (size_t)rowchunk * ROWS_PER_CHUNK * Hc
                               + colchunk * 16 + cf * 4;
        float4 acc = make_float4(0.f, 0.f, 0.f, 0.f);
        #pragma unroll
        for (int i = 0; i < 16; ++i) {
            float4 v = *(const float4*)(base + (size_t)(r0 + 64 * i) * Hc);
            acc.x += v.x; acc.y += v.y; acc.z += v.z; acc.w += v.w;
        }
        // reduce across the 16 r-groups within the wave (lane bits 2..5)
        #pragma unroll
        for (int off = 4; off <= 32; off <<= 1) {
            acc.x += __shfl_xor(acc.x, off);
            acc.y += __shfl_xor(acc.y, off);
            acc.z += __shfl_xor(acc.z, off);
            acc.w += __shfl_xor(acc.w, off);
        }
        __shared__ float4 sm[4][4];
        if ((t & 63) < 4) sm[t >> 6][t & 3] = acc;
        __syncthreads();
        if (t < 4) {
            float4 a = sm[0][t], b = sm[1][t], c = sm[2][t], d = sm[3][t];
            float4 r = make_float4(a.x + b.x + c.x + d.x, a.y + b.y + c.y + d.y,
                                   a.z + b.z + c.z + d.z, a.w + b.w + c.w + d.w);
            *(float4*)(ws + WS_PART + (size_t)rowchunk * Hc + colchunk * 16 + t * 4) = r;
        }
    } else if (bid < B_GH0) {
        int base_row = (bid - B_PRED0) * 16 + (t >> 6) * 4;
        #pragma unroll
        for (int rr = 0; rr < 4; ++rr) {
            int row = base_row + rr;
            float d = warp_dot(pred_proj_w + (size_t)row * Pc, pred_state, Pc);
            if ((t & 63) == 0) out[O_PRED + row] = d;
        }
    } else if (bid < B_CPY0) {
        int base_row = (bid - B_GH0) * 16 + (t >> 6) * 4;
        #pragma unroll
        for (int rr = 0; rr < 4; ++rr) {
            int row = base_row + rr;
            float d = warp_dot(W_hh + (size_t)row * Pc, pred_state, Pc);
            if ((t & 63) == 0) ws[WS_GH + row] = d;
        }
    } else {
        int cb = bid - B_CPY0;               // 0..31
        #pragma unroll
        for (int i = 0; i < 16; ++i) {
            int idx = (cb * 16 + i) * 256 + t;   // covers 64*2048 = 131072
            out[O_MEM + idx] = mem_states[idx];
        }
        if (cb == 0 && t < Nc) {
            double ds = pow(0.999, 8192.0);      // DECAY ** seq_len
            out[O_MEMS + t] = mem_strength[t] * (float)ds;
        }
    }
}

// K2: finalize actual (16 partials per column), prediction_error, e2 partials.
__global__ __launch_bounds__(256) void k2(float* __restrict__ out,
                                          float* __restrict__ ws) {
    const int c = blockIdx.x * 256 + threadIdx.x;   // column 0..2047
    float s = 0.f;
    #pragma unroll
    for (int p = 0; p < RCHUNKS; ++p) s += ws[WS_PART + (size_t)p * Hc + c];
    float actual = s * (1.0f / (float)ROWS);
    ws[WS_ACT + c] = actual;
    float pe = actual - out[O_PRED + c];
    out[O_PERR + c] = pe;
    float e2 = pe * pe;
    #pragma unroll
    for (int off = 32; off; off >>= 1) e2 += __shfl_xor(e2, off);
    __shared__ float sm[4];
    if ((threadIdx.x & 63) == 0) sm[threadIdx.x >> 6] = e2;
    __syncthreads();
    if (threadIdx.x == 0) ws[WS_ERR2 + blockIdx.x] = sm[0] + sm[1] + sm[2] + sm[3];
}

// K3: blocks [0,512): x_gru = input_proj_w @ actual (wave-per-row)
//     block 512:      surprise + slot writes
__global__ __launch_bounds__(256) void k3(const float* __restrict__ input_proj_w,
                                          const float* __restrict__ surprise_scale,
                                          const int* __restrict__ write_ptr,
                                          float* __restrict__ out,
                                          float* __restrict__ ws) {
    const int bid = blockIdx.x;
    if (bid < 512) {
        int row = bid * 4 + (threadIdx.x >> 6);
        float d = warp_dot(input_proj_w + (size_t)row * Hc, ws + WS_ACT, Hc);
        if ((threadIdx.x & 63) == 0) ws[WS_XGRU + row] = d;
    } else {
        __shared__ float s_sur;
        __shared__ int s_slot;
        if (threadIdx.x == 0) {
            float e2 = 0.f;
            #pragma unroll
            for (int i = 0; i < 8; ++i) e2 += ws[WS_ERR2 + i];
            float norm = sqrtf(e2 * (1.0f / (float)Hc));
            float sur = 1.f / (1.f + expf(-surprise_scale[0] * norm));
            out[O_SUR] = sur;
            int slot = write_ptr[0] % Nc;
            if (slot < 0) slot += Nc;
            out[O_MEMS + slot] = sur;
            s_sur = sur;
            s_slot = slot;
        }
        __syncthreads();
        float sur = s_sur;
        int slot = s_slot;
        for (int c = threadIdx.x; c < Hc; c += 256)
            out[O_MEM + (size_t)slot * Hc + c] = ws[WS_ACT + c] * sur;
    }
}

// K4: gi = W_ih @ x_gru + fused GRU combine. 128 blocks; block j owns output
// elements k0=4j..4j+3, computing rows {g*512 + k0 + e} for gate g in {r,z,n}.
__global__ __launch_bounds__(256) void k4(const float* __restrict__ W_ih,
                                          const float* __restrict__ b_ih,
                                          const float* __restrict__ b_hh,
                                          const float* __restrict__ pred_state,
                                          float* __restrict__ out,
                                          float* __restrict__ ws) {
    const int k0 = blockIdx.x * 4;
    const int wave = threadIdx.x >> 6;
    __shared__ float gi_s[12];
    #pragma unroll
    for (int j = 0; j < 3; ++j) {
        int d = wave * 3 + j;           // 0..11
        int g = d >> 2, e = d & 3;
        int row = g * 512 + k0 + e;
        float v = warp_dot(W_ih + (size_t)row * Hc, ws + WS_XGRU, Hc);
        if ((threadIdx.x & 63) == 0) gi_s[d] = v;
    }
    __syncthreads();
    if (threadIdx.x < 4) {
        int k = k0 + threadIdx.x;
        float i_r = gi_s[threadIdx.x]     + b_ih[k];
        float i_z = gi_s[4 + threadIdx.x] + b_ih[512 + k];
        float i_n = gi_s[8 + threadIdx.x] + b_ih[1024 + k];
        float h_r = ws[WS_GH + k]        + b_hh[k];
        float h_z = ws[WS_GH + 512 + k]  + b_hh[512 + k];
        float h_n = ws[WS_GH + 1024 + k] + b_hh[1024 + k];
        float r = 1.f / (1.f + expf(-(i_r + h_r)));
        float z = 1.f / (1.f + expf(-(i_z + h_z)));
        float n = tanhf(i_n + r * h_n);
        float h = pred_state[k];
        out[O_NPS + k] = (1.f - z) * n + z * h;
    }
}

extern "C" void kernel_launch(void* const* d_in, const int* in_sizes, int n_in,
                              void* d_out, int out_size, void* d_ws, size_t ws_size,
                              hipStream_t stream) {
    const float* hs            = (const float*)d_in[0];
    const float* pred_state    = (const float*)d_in[1];
    const float* mem_states    = (const float*)d_in[2];
    const float* mem_strength  = (const float*)d_in[3];
    const float* W_ih          = (const float*)d_in[4];
    const float* W_hh          = (const float*)d_in[5];
    const float* b_ih          = (const float*)d_in[6];
    const float* b_hh          = (const float*)d_in[7];
    const float* pred_proj_w   = (const float*)d_in[8];
    const float* input_proj_w  = (const float*)d_in[9];
    const float* surprise_scale= (const float*)d_in[10];
    const int*   write_ptr     = (const int*)d_in[11];
    float* out = (float*)d_out;
    float* ws  = (float*)d_ws;

    k1<<<K1_GRID, 256, 0, stream>>>(hs, pred_state, mem_states, mem_strength,
                                    W_hh, pred_proj_w, out, ws);
    k2<<<8, 256, 0, stream>>>(out, ws);
    k3<<<513, 256, 0, stream>>>(input_proj_w, surprise_scale, write_ptr, out, ws);
    k4<<<128, 256, 0, stream>>>(W_ih, b_ih, b_hh, pred_state, out, ws);
}